// Round 1
// baseline (220.033 us; speedup 1.0000x reference)
//
#include <hip/hip_runtime.h>
#include <stdint.h>

#define HD   1024
#define LD   4096
#define BATCH 4
#define KLEN 8192           // 2*L
#define LAM  0.1f
#define TAP_CAP 65536
#define NT   16             // K tiles: 1024 / 64

typedef __attribute__((ext_vector_type(8))) short short8x;
typedef __attribute__((ext_vector_type(4))) float float4x;

struct Tap { int hd; float v; };

__device__ inline unsigned short f2bf(float x) {
    union { float f; uint32_t u; } v; v.f = x;
    uint32_t u = v.u;
    u += 0x7fffu + ((u >> 16) & 1u);
    return (unsigned short)(u >> 16);
}

__device__ inline void gload16(const void* g, void* l) {
    __builtin_amdgcn_global_load_lds(
        (const __attribute__((address_space(1))) void*)g,
        (__attribute__((address_space(3))) void*)l,
        16, 0, 0);
}

__device__ inline float silu_f(float x) { return x / (1.0f + __expf(-x)); }

// ---------------- fused: W fp32->bf16 (blocks 0..1023) + kernel scan --------
__global__ void k_prep(const float* __restrict__ kern, int* __restrict__ ntaps,
                       Tap* __restrict__ taps,
                       const float* __restrict__ W, unsigned short* __restrict__ Wbf) {
    if (blockIdx.x < 1024) {
        int i = blockIdx.x * 256 + threadIdx.x;
        const float4* w4 = (const float4*)W;
        float4 a = w4[i * 2], b = w4[i * 2 + 1];
        short8x o;
        o[0] = (short)f2bf(a.x); o[1] = (short)f2bf(a.y);
        o[2] = (short)f2bf(a.z); o[3] = (short)f2bf(a.w);
        o[4] = (short)f2bf(b.x); o[5] = (short)f2bf(b.y);
        o[6] = (short)f2bf(b.z); o[7] = (short)f2bf(b.w);
        *(short8x*)(Wbf + (int64_t)i * 8) = o;
        return;
    }
    int bid = blockIdx.x - 1024;
    const float4* k4 = (const float4*)kern;
    int64_t total4 = (int64_t)HD * KLEN / 4;
    int64_t stride = (int64_t)2048 * 256;
    for (int64_t i = (int64_t)bid * 256 + threadIdx.x; i < total4; i += stride) {
        float4 v = k4[i];
        float vals[4] = {v.x, v.y, v.z, v.w};
#pragma unroll
        for (int j = 0; j < 4; j++) {
            float a = fabsf(vals[j]) - LAM;
            if (a > 0.0f) {
                int e = (int)(i * 4 + j);
                int slot = atomicAdd(ntaps, 1);
                if (slot < TAP_CAP) { taps[slot].hd = e; taps[slot].v = copysignf(a, vals[j]); }
            }
        }
    }
}

// ---------------- V^T build: silu(u*D + sparse conv) -> (B*L, H) bf16 -------
// Generic sparse-conv path inlined (block-uniform branch; nt==0 on this data).
__global__ __launch_bounds__(256) void k_vt(const float* __restrict__ u,
                                            const float* __restrict__ Dv,
                                            const int* __restrict__ ntaps_p,
                                            const Tap* __restrict__ taps,
                                            unsigned short* __restrict__ Vt) {
    __shared__ float T[64 * 65];                 // index h*65 + l
    int nt = *ntaps_p;
    int lt = blockIdx.x * 64;
    int ht = blockIdx.y * 64;
    int b  = blockIdx.z;
    int tid = threadIdx.x;
    int lq = tid & 15;
    int hh = tid >> 4;
#pragma unroll
    for (int r = 0; r < 4; r++) {
        int h = hh + r * 16;
        int hg = ht + h;
        int64_t base = ((int64_t)b * HD + hg) * LD + lt + lq * 4;
        float4 v = *(const float4*)(u + base);
        float d = Dv[hg];
        v.x *= d; v.y *= d; v.z *= d; v.w *= d;
        if (nt != 0) {                           // generic sparse-conv path
            int ncl = min(nt, TAP_CAP);
            float acc[4] = {v.x, v.y, v.z, v.w};
            const float* ub = u + ((int64_t)b * HD + hg) * LD;
            for (int j = 0; j < ncl; j++) {
                int hd = taps[j].hd;
                if ((hd >> 13) != hg) continue;
                int dly = hd & (KLEN - 1);
#pragma unroll
                for (int e = 0; e < 4; e++) {
                    int t = lt + lq * 4 + e;
                    int s = t - dly;
                    if (s < 0) s += KLEN;
                    if (s < LD) acc[e] += taps[j].v * ub[s];
                }
            }
            v.x = acc[0]; v.y = acc[1]; v.z = acc[2]; v.w = acc[3];
        }
        int p = h * 65 + lq * 4;
        T[p]     = silu_f(v.x);
        T[p + 1] = silu_f(v.y);
        T[p + 2] = silu_f(v.z);
        T[p + 3] = silu_f(v.w);
    }
    __syncthreads();
    int h8 = (tid & 7) * 8;
    int nb = tid >> 3;
#pragma unroll
    for (int p = 0; p < 2; p++) {
        int nl = nb + p * 32;
        short8x o;
#pragma unroll
        for (int j = 0; j < 8; j++) o[j] = (short)f2bf(T[(h8 + j) * 65 + nl]);
        int64_t n = (int64_t)b * LD + lt + nl;
        *(short8x*)(Vt + n * HD + ht + h8) = o;
    }
}

// ---------------- GEMM + GLU epilogue: 256-Zrow x 256-col tile, BK=64 -------
// Z = Wbf(2048x1024) * Vt^T(1024x16384); out[b,h,l]=(z_a+b_a)*sigmoid(z_g+b_g)
// Per block: 128 a-rows + 128 g-rows (A-LDS 256 rows) x 256 cols.
// 512 thr (8 waves, 2m x 4n), LDS 128 KiB = 2 bufs x (A 32K + B 32K).
// Pipeline (T3+T4): 2-K-tile-deep global_load_lds prefetch; raw s_barrier
// (NOT __syncthreads -> no vmcnt(0) drain); steady-state s_waitcnt vmcnt(8).
// T1: XCD-chunked block swizzle (512 blocks, 64/XCD; 8 m-blocks sharing a
// Vt panel land on one XCD's L2). T5: setprio(1) around MFMA clusters.
// 8-slot XOR source swizzle (slot s of row r holds k-chunk s^(r&7)) kept
// from the round-0 kernel: measured 0 LDS bank conflicts.
__global__ __launch_bounds__(512, 2) void k_gemm(const unsigned short* __restrict__ Wbf,
                                                 const unsigned short* __restrict__ Vt,
                                                 const float* __restrict__ bvec,
                                                 float* __restrict__ out) {
    __shared__ unsigned short smem[65536];       // 128 KiB: buf b at b*32768 shorts
    int tid  = threadIdx.x;
    int flat = blockIdx.x;                       // 512 blocks, nwg%8==0
    int swz  = (flat & 7) * 64 + (flat >> 3);    // XCD-contiguous chunks of 64
    int m0   = (swz & 7) * 128;                  // 8 m-blocks (m fast within chunk)
    int n0   = (swz >> 3) * 256;                 // 64 n-panels

    // staging: per K-tile 4096 chunks of 16B (A: 2048, B: 2048); 8 per thread.
    // LDS dest = chunk*16B (lane-contiguous, required by global_load_lds).
    const unsigned short* gsrc[8];
#pragma unroll
    for (int i = 0; i < 8; i++) {
        int c = tid + i * 512;
        if (c < 2048) {                          // A: 256 rows x 8 slots
            int r = c >> 3, s = c & 7;
            int kg = s ^ (r & 7);
            int grow = (r < 128) ? (m0 + r) : (1024 + m0 + (r - 128));
            gsrc[i] = Wbf + (int64_t)grow * HD + kg * 8;
        } else {                                 // B: 256 cols x 8 slots
            int cc = c - 2048;
            int col = cc >> 3, s = cc & 7;
            int kg = s ^ (col & 7);
            gsrc[i] = Vt + (int64_t)(n0 + col) * HD + kg * 8;
        }
    }

    int lane = tid & 63;
    int wid  = tid >> 6;                         // 0..7
    int wm = wid >> 2, wn = wid & 3;             // 2 x 4 wave grid
    int l15 = lane & 15, quad = lane >> 4;
    int xr = l15 & 7;                            // row&7 for all frag rows

    int rba[4], rbg[4], rbb[4];                  // row bases (shorts, per buf)
#pragma unroll
    for (int i = 0; i < 4; i++) {
        int ra = wm * 64 + i * 16 + l15;         // 0..127
        rba[i] = ra * 64;
        rbg[i] = (128 + ra) * 64;
        int cb = wn * 64 + i * 16 + l15;         // 0..255
        rbb[i] = 16384 + cb * 64;
    }

    float4x acca[4][4], accg[4][4];
#pragma unroll
    for (int i = 0; i < 4; i++)
#pragma unroll
        for (int j = 0; j < 4; j++) {
            acca[i][j] = (float4x){0.f, 0.f, 0.f, 0.f};
            accg[i][j] = (float4x){0.f, 0.f, 0.f, 0.f};
        }

    auto stage = [&](int buf) {                  // 8 gload16 per thread
        unsigned short* lb = smem + buf * 32768;
#pragma unroll
        for (int i = 0; i < 8; i++) {
            gload16(gsrc[i], lb + (tid + i * 512) * 8);
            gsrc[i] += 64;                       // next K-tile
        }
    };

    auto compute = [&](int buf) {
        const unsigned short* sb = smem + buf * 32768;
#pragma unroll
        for (int ks = 0; ks < 2; ks++) {
            int off = ((ks * 4 + quad) ^ xr) * 8;   // swizzled slot -> shorts
            short8x af[4], bfr[4];
#pragma unroll
            for (int i = 0; i < 4; i++) {
                af[i]  = *(const short8x*)(sb + rba[i] + off);
                bfr[i] = *(const short8x*)(sb + rbb[i] + off);
            }
            __builtin_amdgcn_s_setprio(1);
#pragma unroll
            for (int i = 0; i < 4; i++)
#pragma unroll
                for (int j = 0; j < 4; j++)
                    acca[i][j] = __builtin_amdgcn_mfma_f32_16x16x32_bf16(af[i], bfr[j], acca[i][j], 0, 0, 0);
            __builtin_amdgcn_s_setprio(0);
            short8x gf[4];
#pragma unroll
            for (int i = 0; i < 4; i++)
                gf[i] = *(const short8x*)(sb + rbg[i] + off);
            __builtin_amdgcn_s_setprio(1);
#pragma unroll
            for (int i = 0; i < 4; i++)
#pragma unroll
                for (int j = 0; j < 4; j++)
                    accg[i][j] = __builtin_amdgcn_mfma_f32_16x16x32_bf16(gf[i], bfr[j], accg[i][j], 0, 0, 0);
            __builtin_amdgcn_s_setprio(0);
        }
    };

    stage(0);                                    // tile 0 -> buf0 (8 loads)
    stage(1);                                    // tile 1 -> buf1 (8 loads)
    for (int t = 0; t < NT - 2; t++) {
        // own 8 loads of tile t done (tile t+1's 8 stay in flight), then sync
        asm volatile("s_waitcnt vmcnt(8)" ::: "memory");
        asm volatile("s_barrier" ::: "memory");
        compute(t & 1);
        // drain own ds_reads before signaling: re-stage below overwrites buf
        asm volatile("s_waitcnt lgkmcnt(0)" ::: "memory");
        asm volatile("s_barrier" ::: "memory");
        stage(t & 1);                            // tile t+2 -> buf[t&1]
    }
    asm volatile("s_waitcnt vmcnt(8)" ::: "memory");
    asm volatile("s_barrier" ::: "memory");
    compute(0);                                  // tile 14
    asm volatile("s_waitcnt vmcnt(0)" ::: "memory");
    asm volatile("s_barrier" ::: "memory");
    compute(1);                                  // tile 15

    // epilogue: out[b,h,l] = (a + b_a) * sigmoid(g + b_g)
    int b = n0 >> 12;
#pragma unroll
    for (int i = 0; i < 4; i++) {
        int h = m0 + wm * 64 + i * 16 + quad * 4;
        float ba[4], bg[4];
#pragma unroll
        for (int r = 0; r < 4; r++) { ba[r] = bvec[h + r]; bg[r] = bvec[1024 + h + r]; }
#pragma unroll
        for (int j = 0; j < 4; j++) {
            int n = n0 + wn * 64 + j * 16 + l15;
            int l = n & (LD - 1);
            float* op = out + ((int64_t)b * HD + h) * LD + l;
#pragma unroll
            for (int r = 0; r < 4; r++) {
                float av = acca[i][j][r] + ba[r];
                float gv = accg[i][j][r] + bg[r];
                op[(int64_t)r * LD] = av / (1.0f + __expf(-gv));
            }
        }
    }
}

extern "C" void kernel_launch(void* const* d_in, const int* in_sizes, int n_in,
                              void* d_out, int out_size, void* d_ws, size_t ws_size,
                              hipStream_t stream) {
    const float* u    = (const float*)d_in[0];   // (4,1024,4096)
    const float* kern = (const float*)d_in[1];   // (1,1024,8192)
    const float* Dv   = (const float*)d_in[2];   // (1,1024)
    const float* W    = (const float*)d_in[3];   // (2048,1024)
    const float* bv   = (const float*)d_in[4];   // (2048,)
    float* out = (float*)d_out;                  // (4,1024,4096)

    char* ws = (char*)d_ws;
    int* ntaps = (int*)ws;                                   // [0,256)
    Tap* taps  = (Tap*)(ws + 256);                           // 512 KiB cap
    unsigned short* Wbf = (unsigned short*)(ws + (1 << 20)); // 4 MiB
    unsigned short* Vt  = (unsigned short*)(ws + (8 << 20)); // 32 MiB

    hipMemsetAsync(ntaps, 0, 256, stream);
    hipLaunchKernelGGL(k_prep, dim3(3072),      dim3(256), 0, stream, kern, ntaps, taps, W, Wbf);
    hipLaunchKernelGGL(k_vt,   dim3(64, 16, 4), dim3(256), 0, stream, u, Dv, ntaps, taps, Vt);
    hipLaunchKernelGGL(k_gemm, dim3(512),       dim3(512), 0, stream, Wbf, Vt, bv, out);
}